// Round 8
// baseline (195.679 us; speedup 1.0000x reference)
//
#include <hip/hip_runtime.h>
#include <math.h>

#define Bx 2
#define Sx 2048
#define Dx 1024
#define Hx 16
#define HDx 64
#define Mx (Bx*Sx)   // 4096

typedef __bf16 bf16x8 __attribute__((ext_vector_type(8)));
typedef __bf16 bf16x4 __attribute__((ext_vector_type(4)));
typedef float  f32x4  __attribute__((ext_vector_type(4)));

// 0.125 (1/sqrt(64)) * log2(e): softmax in exp2 domain; folded into Q in GEMM1
#define SCL 0.18033688011112042f

__device__ __forceinline__ void gload_lds16(const __bf16* g, __bf16* l) {
  __builtin_amdgcn_global_load_lds(
      (const __attribute__((address_space(1))) unsigned int*)g,
      (__attribute__((address_space(3))) unsigned int*)l, 16, 0, 0);
}

// ---------------- fp32 -> bf16 conversion / weight concat ----------------
__device__ __forceinline__ void cvt8(const float* s, __bf16* d) {
  float4 a = *(const float4*)s;
  float4 b = *(const float4*)(s + 4);
  bf16x8 o;
  o[0] = (__bf16)a.x; o[1] = (__bf16)a.y; o[2] = (__bf16)a.z; o[3] = (__bf16)a.w;
  o[4] = (__bf16)b.x; o[5] = (__bf16)b.y; o[6] = (__bf16)b.z; o[7] = (__bf16)b.w;
  *(bf16x8*)d = o;
}

__global__ __launch_bounds__(256) void cvt_kernel(
    const float* __restrict__ x, const float* __restrict__ Wq,
    const float* __restrict__ Wk, const float* __restrict__ Wv,
    const float* __restrict__ Wo, const float* __restrict__ bq,
    const float* __restrict__ bk, const float* __restrict__ bv,
    __bf16* __restrict__ xb, __bf16* __restrict__ wqkv,
    __bf16* __restrict__ wob, float* __restrict__ bqkv)
{
  const int bid = blockIdx.x;
  const int t = threadIdx.x;
  const size_t MEG = 1024u * 1024u;
  if (bid < 2048) {
    size_t e = (size_t)bid * 2048 + t * 8;
    cvt8(x + e, xb + e);
  } else if (bid < 3584) {
    size_t e = (size_t)(bid - 2048) * 2048 + t * 8;
    const float* src = (e < MEG) ? (Wq + e) : (e < 2 * MEG) ? (Wk + (e - MEG)) : (Wv + (e - 2 * MEG));
    cvt8(src, wqkv + e);
  } else if (bid < 4096) {
    size_t e = (size_t)(bid - 3584) * 2048 + t * 8;
    cvt8(Wo + e, wob + e);
  } else {
    for (int i = t; i < 3072; i += 256)
      bqkv[i] = (i < 1024) ? bq[i] : (i < 2048) ? bk[i - 1024] : bv[i - 2048];
  }
}

// ---------------- bf16 MFMA GEMM, stage-ahead pipelined (unchanged) ----------
template<int TM, int TN, int MODE>
__global__ __launch_bounds__(256) void gemm_k(
    const __bf16* __restrict__ A, const __bf16* __restrict__ W,
    const float* __restrict__ bias, float* __restrict__ Cf,
    __bf16* __restrict__ Cb, __bf16* __restrict__ vT,
    int M, int N, int K, int ldc)
{
  __shared__ __align__(16) char smem[2 * (TM + TN) * 64 * 2];
  __bf16* AsB = (__bf16*)smem;

  constexpr int MS = TM / 32;
  constexpr int NS = TN / 32;
  const int tid = threadIdx.x;
  const int lane = tid & 63, wave = tid >> 6;
  const int l16 = lane & 15, quad = lane >> 4;
  const int wm = (wave >> 1) * (TM / 2);
  const int wn = (wave & 1) * (TN / 2);
  const int swz = l16 & 7;

  // 64-block supertile swizzle (8 m-tiles x 8 n-tiles)
  const int lid = blockIdx.y * gridDim.x + blockIdx.x;
  const int g8 = lid >> 6;
  const int r64 = lid & 63;
  const int gpm = (int)gridDim.y >> 3;
  const int gm = g8 % gpm;
  const int gn = g8 / gpm;
  const int m0 = (gm * 8 + (r64 & 7)) * TM;
  const int n0 = (gn * 8 + (r64 >> 3)) * TN;

  const f32x4 zero = {0.f, 0.f, 0.f, 0.f};
  f32x4 acc[MS][NS];
#pragma unroll
  for (int i = 0; i < MS; ++i)
#pragma unroll
    for (int j = 0; j < NS; ++j) acc[i][j] = zero;

  const int srow = tid >> 3;
  const int scs = (tid & 7) ^ (srow & 7);
  const __bf16* Ag = A + (size_t)(m0 + srow) * K + scs * 8;
  const __bf16* Wg = W + (size_t)(n0 + srow) * K + scs * 8;

#define G_STAGE(k0_, b_)                                                        \
  { __bf16* As_ = AsB + (b_) * (TM + TN) * 64;                                  \
    __bf16* Bs_ = As_ + TM * 64;                                                \
    _Pragma("unroll")                                                           \
    for (int i = 0; i < TM / 32; ++i)                                           \
      gload_lds16(Ag + (size_t)(i * 32) * K + (k0_), &As_[(i * 256 + tid) * 8]);\
    _Pragma("unroll")                                                           \
    for (int i = 0; i < TN / 32; ++i)                                           \
      gload_lds16(Wg + (size_t)(i * 32) * K + (k0_), &Bs_[(i * 256 + tid) * 8]); }

  const int NT = K >> 6;
  G_STAGE(0, 0)
  __syncthreads();

  for (int t = 0; t < NT; ++t) {
    if (t + 1 < NT) G_STAGE((t + 1) << 6, (t + 1) & 1)
    const __bf16* As_ = AsB + (t & 1) * (TM + TN) * 64;
    const __bf16* Bs_ = As_ + TM * 64;
#pragma unroll
    for (int hk = 0; hk < 2; ++hk) {
      const int ph = ((hk * 4 + quad) ^ swz) * 8;
      bf16x8 af[MS], bfr[NS];
#pragma unroll
      for (int i = 0; i < MS; ++i)
        af[i] = *(const bf16x8*)&As_[(wm + i * 16 + l16) * 64 + ph];
#pragma unroll
      for (int j = 0; j < NS; ++j)
        bfr[j] = *(const bf16x8*)&Bs_[(wn + j * 16 + l16) * 64 + ph];
#pragma unroll
      for (int i = 0; i < MS; ++i)
#pragma unroll
        for (int j = 0; j < NS; ++j)
          acc[i][j] = __builtin_amdgcn_mfma_f32_16x16x32_bf16(af[i], bfr[j], acc[i][j], 0, 0, 0);
    }
    __syncthreads();   // (a) everyone done with buf t; (b) stage(t+1) drained
  }

  // ---- epilogue: stage C tile in LDS (aliases staging bufs), 16B stores ----
  if (MODE == 0) {
    float* Cs = (float*)smem;          // [TM][TN+4]
    constexpr int cst = TN + 4;
#pragma unroll
    for (int j = 0; j < NS; ++j) {
      const int c = wn + j * 16 + l16;
      const float bv_ = bias[n0 + c];
#pragma unroll
      for (int i = 0; i < MS; ++i) {
        const int r0 = wm + i * 16 + quad * 4;
#pragma unroll
        for (int g = 0; g < 4; ++g)
          Cs[(r0 + g) * cst + c] = acc[i][j][g] + bv_;
      }
    }
    __syncthreads();
    constexpr int passes = TM * TN / (256 * 4);
#pragma unroll
    for (int p = 0; p < passes; ++p) {
      const int slot = p * 256 + tid;
      const int row = slot / (TN / 4);
      const int col4 = (slot % (TN / 4)) * 4;
      f32x4 v = *(const f32x4*)&Cs[row * cst + col4];
      *(f32x4*)&Cf[(size_t)(m0 + row) * ldc + n0 + col4] = v;
    }
  } else {
    __bf16* Cs = (__bf16*)smem;
    constexpr int cst = TN + 8;
    const bool vtile = (n0 >= 2048);
    if (!vtile) {
#pragma unroll
      for (int j = 0; j < NS; ++j) {
        const int c = wn + j * 16 + l16;
        const float bv_ = bias[n0 + c];
        const float sc = ((n0 + c) < 1024) ? SCL : 1.0f;
#pragma unroll
      for (int i = 0; i < MS; ++i) {
          const int r0 = wm + i * 16 + quad * 4;
#pragma unroll
          for (int g = 0; g < 4; ++g)
            Cs[(r0 + g) * cst + c] = (__bf16)((acc[i][j][g] + bv_) * sc);
        }
      }
      __syncthreads();
      constexpr int passes = TM * TN / (256 * 8);
#pragma unroll
      for (int p = 0; p < passes; ++p) {
        const int slot = p * 256 + tid;
        const int row = slot / (TN / 8);
        const int col8 = (slot % (TN / 8)) * 8;
        bf16x8 v = *(const bf16x8*)&Cs[row * cst + col8];
        *(bf16x8*)&Cb[(size_t)(m0 + row) * 3072 + n0 + col8] = v;
      }
    } else {
      constexpr int cstT = TM + 8;
#pragma unroll
      for (int j = 0; j < NS; ++j) {
        const int c = wn + j * 16 + l16;
        const float bv_ = bias[n0 + c];
#pragma unroll
        for (int i = 0; i < MS; ++i) {
          const int r0 = wm + i * 16 + quad * 4;
#pragma unroll
          for (int g = 0; g < 4; ++g)
            Cs[c * cstT + r0 + g] = (__bf16)(acc[i][j][g] + bv_);
        }
      }
      __syncthreads();
      const int bb = m0 >> 11, ml = m0 & 2047;
      constexpr int passes = TM * TN / (256 * 8);
#pragma unroll
      for (int p = 0; p < passes; ++p) {
        const int slot = p * 256 + tid;
        const int dd = slot / (TM / 8);
        const int ss8 = (slot % (TM / 8)) * 8;
        bf16x8 v = *(const bf16x8*)&Cs[dd * cstT + ss8];
        const int c2 = n0 - 2048 + dd;
        const int hh = c2 >> 6, ddd = c2 & 63;
        *(bf16x8*)&vT[((size_t)(bb * 16 + hh) * 64 + ddd) * 2048 + ml + ss8] = v;
      }
    }
  }
}

// ---------------- MFMA flash attention, barrier-free register-P ------------
// r18: seven structures (r10-r17) pinned at >=42us with NO pipe saturated.
// The shared invariant was barriered lockstep: 4 waves/block rendezvous every
// tile while each SIMD hosts waves of 3-4 DIFFERENT blocks -> inter-block
// interference x intra-block lockstep. Fix: register-P formulation (r15) needs
// only per-wave-private K rows / V key-slices -> load them DIRECTLY from
// L2-resident global into fragments. NO LDS, NO __syncthreads in the main
// loop; waves fully independent and self-paced; compiler pipelines freely
// (loads issue before the ~220cyc exp chain = L2 latency cover). LDS only for
// the one-time epilogue O/l reduction (33 KB). Read volume unchanged (each
// K/V tile read exactly once per block, just per-lane instead of gload_lds).
__global__ __launch_bounds__(256, 3) void attn_mfma(
    const __bf16* __restrict__ qkv, const __bf16* __restrict__ vT,
    __bf16* __restrict__ zb)
{
  __shared__ float redA[4096];   // 16 KB
  __shared__ float redB[4096];   // 16 KB
  __shared__ float lred[256];    // 1 KB

  const int tid = threadIdx.x;
  const int lane = tid & 63, wave = tid >> 6;
  const int l16 = lane & 15, quad = lane >> 4;
  const int bx = blockIdx.x;
  const int qt = 31 - (bx >> 5);      // heavy q-tiles dispatched first
  const int bh = bx & 31;
  const int h = bh & 15, b = bh >> 4;
  const int q0 = qt * 64;

  const __bf16* qg = qkv + (size_t)b * 2048 * 3072 + h * 64;
  const __bf16* kg = qg + 1024;
  const __bf16* vg = vT + (size_t)bh * 64 * 2048;

  // this wave's K row (key = t*64 + wave*16 + l16)
  const __bf16* krow = kg + (size_t)(wave * 16 + l16) * 3072;
  const __bf16 ZB = (__bf16)0.0f;

  // Q fragments direct from global (r17-verified layout: swizzle cancels)
  bf16x8 qf0[4], qf1[4];
#pragma unroll
  for (int n = 0; n < 4; ++n) {
    const __bf16* qr = qg + (size_t)(q0 + n * 16 + l16) * 3072;
    qf0[n] = *(const bf16x8*)&qr[quad * 8];
    qf1[n] = *(const bf16x8*)&qr[(quad + 4) * 8];
  }

  const f32x4 zero = {0.f, 0.f, 0.f, 0.f};
  f32x4 acc[4][4];                 // partial O^T: [d=jt*16+quad*4+g][q=n*16+l16]
#pragma unroll
  for (int jt = 0; jt < 4; ++jt)
#pragma unroll
    for (int n = 0; n < 4; ++n) acc[jt][n] = zero;
  float lacc[4] = {0.f, 0.f, 0.f, 0.f};
  f32x4 s[4];                      // S^T: [key=wave*16+quad*4+g][q=n*16+l16]
  bf16x8 pb[4];                    // exp(S) as PV B-frags (upper 4 k-slots 0)
  bf16x4 vf[4];                    // V frags: [d=jt*16+l16][4 keys]
  bf16x8 kf0, kf1;

#define LOAD_K(kt_)                                                             \
  { const __bf16* kp = krow + (size_t)(kt_) * 64 * 3072;                        \
    kf0 = *(const bf16x8*)&kp[quad * 8];                                        \
    kf1 = *(const bf16x8*)&kp[(quad + 4) * 8]; }

#define LOAD_V(kt_)                                                             \
  { _Pragma("unroll")                                                           \
    for (int jt = 0; jt < 4; ++jt)                                              \
      vf[jt] = *(const bf16x4*)&vg[(size_t)(jt * 16 + l16) * 2048               \
                                   + (kt_) * 64 + wave * 16 + quad * 4]; }

#define S_TILE()                                                                \
  { __builtin_amdgcn_s_setprio(1);                                              \
    _Pragma("unroll")                                                           \
    for (int n = 0; n < 4; ++n) {                                               \
      s[n] = zero;                                                              \
      s[n] = __builtin_amdgcn_mfma_f32_16x16x32_bf16(kf0, qf0[n], s[n], 0, 0, 0);\
      s[n] = __builtin_amdgcn_mfma_f32_16x16x32_bf16(kf1, qf1[n], s[n], 0, 0, 0);\
    }                                                                           \
    __builtin_amdgcn_s_setprio(0); }

  const int kqb = wave * 16 + quad * 4;   // wave's key base (tile-local)

#define EXP_PB(DIAG)                                                            \
  { _Pragma("unroll")                                                           \
    for (int n = 0; n < 4; ++n) {                                               \
      const int ql = n * 16 + l16;                                              \
      float e0 = __builtin_exp2f(s[n][0]);                                      \
      float e1 = __builtin_exp2f(s[n][1]);                                      \
      float e2 = __builtin_exp2f(s[n][2]);                                      \
      float e3 = __builtin_exp2f(s[n][3]);                                      \
      if (DIAG) {                                                               \
        if (kqb + 0 > ql) e0 = 0.f;                                             \
        if (kqb + 1 > ql) e1 = 0.f;                                             \
        if (kqb + 2 > ql) e2 = 0.f;                                             \
        if (kqb + 3 > ql) e3 = 0.f;                                             \
      }                                                                         \
      pb[n] = (bf16x8){(__bf16)e0, (__bf16)e1, (__bf16)e2, (__bf16)e3,          \
                       ZB, ZB, ZB, ZB};                                         \
      lacc[n] += (e0 + e1) + (e2 + e3);                                         \
    } }

#define PV_TILE()                                                               \
  { __builtin_amdgcn_s_setprio(1);                                              \
    _Pragma("unroll")                                                           \
    for (int jt = 0; jt < 4; ++jt) {                                            \
      bf16x8 av = (bf16x8){vf[jt][0], vf[jt][1], vf[jt][2], vf[jt][3],          \
                           ZB, ZB, ZB, ZB};                                     \
      _Pragma("unroll")                                                         \
      for (int n = 0; n < 4; ++n)                                               \
        acc[jt][n] = __builtin_amdgcn_mfma_f32_16x16x32_bf16(av, pb[n], acc[jt][n], 0, 0, 0); \
    }                                                                           \
    __builtin_amdgcn_s_setprio(0); }

  LOAD_K(0)
  S_TILE()                          // s = tile 0

  for (int t = 0; t < qt; ++t) {
    LOAD_K(t + 1)                   // issue loads early; exp chain covers
    LOAD_V(t)
    EXP_PB(false)                   // pb = exp(s(t))
    S_TILE()                        // s = tile t+1 (from kf just loaded)
    PV_TILE()                       // acc += pb * V(t)
  }
  // diagonal (masked) tile
  LOAD_V(qt)
  EXP_PB(true)
  PV_TILE()

  // ---- one-time cross-wave reduction of partial O (and l) ----
#pragma unroll
  for (int n = 0; n < 4; ++n) {
    float v = lacc[n];
    v += __shfl_xor(v, 16);
    v += __shfl_xor(v, 32);
    lacc[n] = v;
  }
  if (quad == 0) {
#pragma unroll
    for (int n = 0; n < 4; ++n) lred[wave * 64 + n * 16 + l16] = lacc[n];
  }

#define WR_ACC(dst)                                                             \
  { _Pragma("unroll")                                                           \
    for (int jt = 0; jt < 4; ++jt)                                              \
      _Pragma("unroll")                                                         \
      for (int n = 0; n < 4; ++n)                                               \
        *(f32x4*)&dst[(jt * 4 + n) * 256 + lane * 4] = acc[jt][n]; }
#define ADD_ACC(srcp)                                                           \
  { _Pragma("unroll")                                                           \
    for (int jt = 0; jt < 4; ++jt)                                              \
      _Pragma("unroll")                                                         \
      for (int n = 0; n < 4; ++n) {                                             \
        f32x4 tmp = *(const f32x4*)&srcp[(jt * 4 + n) * 256 + lane * 4];        \
        acc[jt][n] += tmp;                                                      \
      } }

  if (wave == 1) WR_ACC(redA)
  if (wave == 3) WR_ACC(redB)
  __syncthreads();
  if (wave == 0) ADD_ACC(redA)
  if (wave == 2) ADD_ACC(redB)
  __syncthreads();
  if (wave == 2) WR_ACC(redA)
  __syncthreads();
  if (wave == 0) {
    ADD_ACC(redA)
    float inv[4];
#pragma unroll
    for (int n = 0; n < 4; ++n) {
      const float lsum = lred[n * 16 + l16] + lred[64 + n * 16 + l16]
                       + lred[128 + n * 16 + l16] + lred[192 + n * 16 + l16];
      inv[n] = 1.0f / lsum;
    }
#pragma unroll
    for (int jt = 0; jt < 4; ++jt)
#pragma unroll
      for (int n = 0; n < 4; ++n) {
        bf16x4 ov = (bf16x4){(__bf16)(acc[jt][n][0] * inv[n]),
                             (__bf16)(acc[jt][n][1] * inv[n]),
                             (__bf16)(acc[jt][n][2] * inv[n]),
                             (__bf16)(acc[jt][n][3] * inv[n])};
        *(bf16x4*)&zb[(size_t)(b * 2048 + q0 + n * 16 + l16) * 1024
                      + h * 64 + jt * 16 + quad * 4] = ov;
      }
  }
}

// ---------------- launch ----------------
extern "C" void kernel_launch(void* const* d_in, const int* in_sizes, int n_in,
                              void* d_out, int out_size, void* d_ws, size_t ws_size,
                              hipStream_t stream) {
  (void)in_sizes; (void)n_in; (void)out_size; (void)ws_size;
  const float* x  = (const float*)d_in[0];
  const float* Wq = (const float*)d_in[1];
  const float* bq = (const float*)d_in[2];
  const float* Wk = (const float*)d_in[3];
  const float* bk = (const float*)d_in[4];
  const float* Wv = (const float*)d_in[5];
  const float* bv = (const float*)d_in[6];
  const float* Wo = (const float*)d_in[7];
  const float* bo = (const float*)d_in[8];

  char* ws = (char*)d_ws;
  __bf16* xb   = (__bf16*)(ws);                        // 8 MB
  __bf16* wqkv = (__bf16*)(ws + (8ull  << 20));        // 6 MB
  __bf16* wob  = (__bf16*)(ws + (14ull << 20));        // 2 MB
  float*  bqkv = (float*) (ws + (16ull << 20));        // 12 KB
  __bf16* qkv  = (__bf16*)(ws + (17ull << 20));        // 24 MB
  __bf16* vT   = (__bf16*)(ws + (41ull << 20));        // 8 MB  [bh][64][2048]
  __bf16* zb   = (__bf16*)(ws + (49ull << 20));        // 8 MB  (total 57 MB)

  cvt_kernel<<<4097, 256, 0, stream>>>(x, Wq, Wk, Wv, Wo, bq, bk, bv,
                                       xb, wqkv, wob, bqkv);
  gemm_k<128, 128, 1><<<dim3(24, 32), 256, 0, stream>>>(
      xb, wqkv, bqkv, nullptr, qkv, vT, Mx, 3072, 1024, 0);
  attn_mfma<<<1024, 256, 0, stream>>>(qkv, vT, zb);
  gemm_k<128, 64, 0><<<dim3(16, 32), 256, 0, stream>>>(
      zb, wob, bo, (float*)d_out, nullptr, nullptr, Mx, 1024, 1024, 1024);
}

// Round 10
// 178.685 us; speedup vs baseline: 1.0951x; 1.0951x over previous
//
#include <hip/hip_runtime.h>
#include <math.h>

#define Bx 2
#define Sx 2048
#define Dx 1024
#define Hx 16
#define HDx 64
#define Mx (Bx*Sx)   // 4096

typedef __bf16 bf16x8 __attribute__((ext_vector_type(8)));
typedef __bf16 bf16x4 __attribute__((ext_vector_type(4)));
typedef float  f32x4  __attribute__((ext_vector_type(4)));

// 0.125 (1/sqrt(64)) * log2(e): softmax in exp2 domain; folded into Q in GEMM1
#define SCL 0.18033688011112042f

__device__ __forceinline__ void gload_lds16(const __bf16* g, __bf16* l) {
  __builtin_amdgcn_global_load_lds(
      (const __attribute__((address_space(1))) unsigned int*)g,
      (__attribute__((address_space(3))) unsigned int*)l, 16, 0, 0);
}

// ---------------- fp32 -> bf16 conversion / weight concat ----------------
__device__ __forceinline__ void cvt8(const float* s, __bf16* d) {
  float4 a = *(const float4*)s;
  float4 b = *(const float4*)(s + 4);
  bf16x8 o;
  o[0] = (__bf16)a.x; o[1] = (__bf16)a.y; o[2] = (__bf16)a.z; o[3] = (__bf16)a.w;
  o[4] = (__bf16)b.x; o[5] = (__bf16)b.y; o[6] = (__bf16)b.z; o[7] = (__bf16)b.w;
  *(bf16x8*)d = o;
}

__global__ __launch_bounds__(256) void cvt_kernel(
    const float* __restrict__ x, const float* __restrict__ Wq,
    const float* __restrict__ Wk, const float* __restrict__ Wv,
    const float* __restrict__ Wo, const float* __restrict__ bq,
    const float* __restrict__ bk, const float* __restrict__ bv,
    __bf16* __restrict__ xb, __bf16* __restrict__ wqkv,
    __bf16* __restrict__ wob, float* __restrict__ bqkv)
{
  const int bid = blockIdx.x;
  const int t = threadIdx.x;
  const size_t MEG = 1024u * 1024u;
  if (bid < 2048) {
    size_t e = (size_t)bid * 2048 + t * 8;
    cvt8(x + e, xb + e);
  } else if (bid < 3584) {
    size_t e = (size_t)(bid - 2048) * 2048 + t * 8;
    const float* src = (e < MEG) ? (Wq + e) : (e < 2 * MEG) ? (Wk + (e - MEG)) : (Wv + (e - 2 * MEG));
    cvt8(src, wqkv + e);
  } else if (bid < 4096) {
    size_t e = (size_t)(bid - 3584) * 2048 + t * 8;
    cvt8(Wo + e, wob + e);
  } else {
    for (int i = t; i < 3072; i += 256)
      bqkv[i] = (i < 1024) ? bq[i] : (i < 2048) ? bk[i - 1024] : bv[i - 2048];
  }
}

// ---------------- bf16 MFMA GEMM, stage-ahead pipelined (GEMM2 only) --------
template<int TM, int TN, int MODE>
__global__ __launch_bounds__(256) void gemm_k(
    const __bf16* __restrict__ A, const __bf16* __restrict__ W,
    const float* __restrict__ bias, float* __restrict__ Cf,
    __bf16* __restrict__ Cb, __bf16* __restrict__ vT,
    int M, int N, int K, int ldc)
{
  __shared__ __align__(16) char smem[2 * (TM + TN) * 64 * 2];
  __bf16* AsB = (__bf16*)smem;

  constexpr int MS = TM / 32;
  constexpr int NS = TN / 32;
  const int tid = threadIdx.x;
  const int lane = tid & 63, wave = tid >> 6;
  const int l16 = lane & 15, quad = lane >> 4;
  const int wm = (wave >> 1) * (TM / 2);
  const int wn = (wave & 1) * (TN / 2);
  const int swz = l16 & 7;

  // 64-block supertile swizzle (8 m-tiles x 8 n-tiles)
  const int lid = blockIdx.y * gridDim.x + blockIdx.x;
  const int g8 = lid >> 6;
  const int r64 = lid & 63;
  const int gpm = (int)gridDim.y >> 3;
  const int gm = g8 % gpm;
  const int gn = g8 / gpm;
  const int m0 = (gm * 8 + (r64 & 7)) * TM;
  const int n0 = (gn * 8 + (r64 >> 3)) * TN;

  const f32x4 zero = {0.f, 0.f, 0.f, 0.f};
  f32x4 acc[MS][NS];
#pragma unroll
  for (int i = 0; i < MS; ++i)
#pragma unroll
    for (int j = 0; j < NS; ++j) acc[i][j] = zero;

  const int srow = tid >> 3;
  const int scs = (tid & 7) ^ (srow & 7);
  const __bf16* Ag = A + (size_t)(m0 + srow) * K + scs * 8;
  const __bf16* Wg = W + (size_t)(n0 + srow) * K + scs * 8;

#define G_STAGE(k0_, b_)                                                        \
  { __bf16* As_ = AsB + (b_) * (TM + TN) * 64;                                  \
    __bf16* Bs_ = As_ + TM * 64;                                                \
    _Pragma("unroll")                                                           \
    for (int i = 0; i < TM / 32; ++i)                                           \
      gload_lds16(Ag + (size_t)(i * 32) * K + (k0_), &As_[(i * 256 + tid) * 8]);\
    _Pragma("unroll")                                                           \
    for (int i = 0; i < TN / 32; ++i)                                           \
      gload_lds16(Wg + (size_t)(i * 32) * K + (k0_), &Bs_[(i * 256 + tid) * 8]); }

  const int NT = K >> 6;
  G_STAGE(0, 0)
  __syncthreads();

  for (int t = 0; t < NT; ++t) {
    if (t + 1 < NT) G_STAGE((t + 1) << 6, (t + 1) & 1)
    const __bf16* As_ = AsB + (t & 1) * (TM + TN) * 64;
    const __bf16* Bs_ = As_ + TM * 64;
#pragma unroll
    for (int hk = 0; hk < 2; ++hk) {
      const int ph = ((hk * 4 + quad) ^ swz) * 8;
      bf16x8 af[MS], bfr[NS];
#pragma unroll
      for (int i = 0; i < MS; ++i)
        af[i] = *(const bf16x8*)&As_[(wm + i * 16 + l16) * 64 + ph];
#pragma unroll
      for (int j = 0; j < NS; ++j)
        bfr[j] = *(const bf16x8*)&Bs_[(wn + j * 16 + l16) * 64 + ph];
#pragma unroll
      for (int i = 0; i < MS; ++i)
#pragma unroll
        for (int j = 0; j < NS; ++j)
          acc[i][j] = __builtin_amdgcn_mfma_f32_16x16x32_bf16(af[i], bfr[j], acc[i][j], 0, 0, 0);
    }
    __syncthreads();   // (a) everyone done with buf t; (b) stage(t+1) drained
  }

  // ---- epilogue: stage C tile in LDS (aliases staging bufs), 16B stores ----
  if (MODE == 0) {
    float* Cs = (float*)smem;          // [TM][TN+4]
    constexpr int cst = TN + 4;
#pragma unroll
    for (int j = 0; j < NS; ++j) {
      const int c = wn + j * 16 + l16;
      const float bv_ = bias[n0 + c];
#pragma unroll
      for (int i = 0; i < MS; ++i) {
        const int r0 = wm + i * 16 + quad * 4;
#pragma unroll
        for (int g = 0; g < 4; ++g)
          Cs[(r0 + g) * cst + c] = acc[i][j][g] + bv_;
      }
    }
    __syncthreads();
    constexpr int passes = TM * TN / (256 * 4);
#pragma unroll
    for (int p = 0; p < passes; ++p) {
      const int slot = p * 256 + tid;
      const int row = slot / (TN / 4);
      const int col4 = (slot % (TN / 4)) * 4;
      f32x4 v = *(const f32x4*)&Cs[row * cst + col4];
      *(f32x4*)&Cf[(size_t)(m0 + row) * ldc + n0 + col4] = v;
    }
  } else {
    __bf16* Cs = (__bf16*)smem;
    constexpr int cst = TN + 8;
    const bool vtile = (n0 >= 2048);
    if (!vtile) {
#pragma unroll
      for (int j = 0; j < NS; ++j) {
        const int c = wn + j * 16 + l16;
        const float bv_ = bias[n0 + c];
        const float sc = ((n0 + c) < 1024) ? SCL : 1.0f;
#pragma unroll
        for (int i = 0; i < MS; ++i) {
          const int r0 = wm + i * 16 + quad * 4;
#pragma unroll
          for (int g = 0; g < 4; ++g)
            Cs[(r0 + g) * cst + c] = (__bf16)((acc[i][j][g] + bv_) * sc);
        }
      }
      __syncthreads();
      constexpr int passes = TM * TN / (256 * 8);
#pragma unroll
      for (int p = 0; p < passes; ++p) {
        const int slot = p * 256 + tid;
        const int row = slot / (TN / 8);
        const int col8 = (slot % (TN / 8)) * 8;
        bf16x8 v = *(const bf16x8*)&Cs[row * cst + col8];
        *(bf16x8*)&Cb[(size_t)(m0 + row) * 3072 + n0 + col8] = v;
      }
    } else {
      constexpr int cstT = TM + 8;
#pragma unroll
      for (int j = 0; j < NS; ++j) {
        const int c = wn + j * 16 + l16;
        const float bv_ = bias[n0 + c];
#pragma unroll
        for (int i = 0; i < MS; ++i) {
          const int r0 = wm + i * 16 + quad * 4;
#pragma unroll
          for (int g = 0; g < 4; ++g)
            Cs[c * cstT + r0 + g] = (__bf16)(acc[i][j][g] + bv_);
        }
      }
      __syncthreads();
      const int bb = m0 >> 11, ml = m0 & 2047;
      constexpr int passes = TM * TN / (256 * 8);
#pragma unroll
      for (int p = 0; p < passes; ++p) {
        const int slot = p * 256 + tid;
        const int dd = slot / (TM / 8);
        const int ss8 = (slot % (TM / 8)) * 8;
        bf16x8 v = *(const bf16x8*)&Cs[dd * cstT + ss8];
        const int c2 = n0 - 2048 + dd;
        const int hh = c2 >> 6, ddd = c2 & 63;
        *(bf16x8*)&vT[((size_t)(bb * 16 + hh) * 64 + ddd) * 2048 + ml + ss8] = v;
      }
    }
  }
}

// ---------------- GEMM1: 8-phase 256x256 (T3+T4+T5), r20 race-fixed ---------
// r19 BUG: staged A-lo(kt+2) in phase 1, but A-half regions are read in phases
// 1 AND 3 (per-wave split) -> the distance-2 same-buffer overwrite could land
// before the phase-3 reads. FIX: a region may be staged only AFTER its last
// read phase (barrier-ordered): B halves fully read by end of P2 -> staged in
// P3; A halves fully read by end of P3 -> staged in P4. vmcnt(8) once per
// K-tile: at KTB(kt) P4 the per-wave queue is exactly [kt+1's 8, kt+2's 8];
// vmcnt(8) confirms kt+1 before KTB(kt+1) reads it (induction from prologue's
// full stage of tiles 0,1 + vmcnt(0); tail kt=14 drains with vmcnt(0)).
// Intra-phase: P3 reads A / stages B (disjoint); P4's A stages are issued
// after the P3-end barrier, behind which all A ds_reads completed (consumed
// by P3 MFMA). Stages now fly ~5 phases (~600+ cyc) before confirmation.
__global__ __launch_bounds__(512, 1) void gemm8_qkv(
    const __bf16* __restrict__ A, const __bf16* __restrict__ W,
    const float* __restrict__ bias, __bf16* __restrict__ Cb,
    __bf16* __restrict__ vT)
{
  __shared__ __align__(16) char smem8[131072];

  const int tid = threadIdx.x;
  const int lane = tid & 63;
  const int wid = tid >> 6;            // 0..7
  const int l16 = lane & 15, quad = lane >> 4;
  const int wm = (wid >> 2) * 128;     // wave row base (0 or 128)
  const int wn = (wid & 3) * 64;       // wave col base
  const int swz = l16 & 7;

  // XCD-bijective swizzle (192 blocks, 192 % 8 == 0)
  const int lid = blockIdx.x;
  const int wg = (lid & 7) * 24 + (lid >> 3);
  const int m0 = (wg / 12) * 256;
  const int n0 = (wg % 12) * 256;

  // staging: 2 slots/thread per half-tile (128 rows x 64 cols)
  const int r0 = tid >> 3;             // 0..63
  const int r1 = r0 + 64;              // 64..127
  const int ch8 = tid & 7;
  const int cs0 = ch8 ^ (r0 & 7);
  const int cs1 = ch8 ^ (r1 & 7);

  const __bf16* Ag0 = A + (size_t)(m0 + r0) * 1024 + cs0 * 8;
  const __bf16* Ag1 = A + (size_t)(m0 + r1) * 1024 + cs1 * 8;
  const __bf16* Wg0 = W + (size_t)(n0 + r0) * 1024 + cs0 * 8;
  const __bf16* Wg1 = W + (size_t)(n0 + r1) * 1024 + cs1 * 8;

#define LA8(b) ((__bf16*)(smem8 + (b) * 65536))
#define LB8(b) ((__bf16*)(smem8 + (b) * 65536 + 32768))

#define STG_A(half, kt) {                                                      \
    __bf16* d_ = LA8((kt) & 1) + (half) * 8192;                                \
    const size_t o_ = (size_t)(half) * 131072 + (size_t)(kt) * 64;             \
    gload_lds16(Ag0 + o_, d_ + tid * 8);                                       \
    gload_lds16(Ag1 + o_, d_ + (512 + tid) * 8); }
#define STG_B(half, kt) {                                                      \
    __bf16* d_ = LB8((kt) & 1) + (half) * 8192;                                \
    const size_t o_ = (size_t)(half) * 131072 + (size_t)(kt) * 64;             \
    gload_lds16(Wg0 + o_, d_ + tid * 8);                                       \
    gload_lds16(Wg1 + o_, d_ + (512 + tid) * 8); }

#define RDA(f, kh, mh, b) (*(const bf16x8*)&LA8(b)[(wm + ((mh)*4+(f))*16 + l16) * 64 + ((((kh)*4+quad)) ^ swz) * 8])
#define RDB(n, kh, nh, b) (*(const bf16x8*)&LB8(b)[(wn + ((nh)*2+(n))*16 + l16) * 64 + ((((kh)*4+quad)) ^ swz) * 8])

  const f32x4 zero = {0.f, 0.f, 0.f, 0.f};
  f32x4 acc[8][4];
#pragma unroll
  for (int i = 0; i < 8; ++i)
#pragma unroll
    for (int j = 0; j < 4; ++j) acc[i][j] = zero;

#define MQ(a_, b_, mh, nh) {                                                   \
    _Pragma("unroll")                                                          \
    for (int f_ = 0; f_ < 4; ++f_)                                             \
      _Pragma("unroll")                                                        \
      for (int n_ = 0; n_ < 2; ++n_) {                                         \
        acc[(mh)*4+f_][(nh)*2+n_] = __builtin_amdgcn_mfma_f32_16x16x32_bf16(   \
            a_[f_][0], b_[n_][0], acc[(mh)*4+f_][(nh)*2+n_], 0, 0, 0);         \
        acc[(mh)*4+f_][(nh)*2+n_] = __builtin_amdgcn_mfma_f32_16x16x32_bf16(   \
            a_[f_][1], b_[n_][1], acc[(mh)*4+f_][(nh)*2+n_], 0, 0, 0); } }

#define KTB(kt, cur) {                                                         \
    const bool st_ = (kt) < 14;                                                \
    bf16x8 af[4][2], bfl[2][2], bfh[2][2];                                     \
    /* P1: read A(wave half, lo 64 rows) + B(lo 32 rows); NO staging */        \
    _Pragma("unroll")                                                          \
    for (int f_ = 0; f_ < 4; ++f_) { af[f_][0] = RDA(f_,0,0,cur); af[f_][1] = RDA(f_,1,0,cur); } \
    _Pragma("unroll")                                                          \
    for (int n_ = 0; n_ < 2; ++n_) { bfl[n_][0] = RDB(n_,0,0,cur); bfl[n_][1] = RDB(n_,1,0,cur); } \
    __builtin_amdgcn_s_barrier();                                              \
    __builtin_amdgcn_s_setprio(1);                                             \
    MQ(af, bfl, 0, 0)                                                          \
    __builtin_amdgcn_s_setprio(0);                                             \
    __builtin_amdgcn_s_barrier();                                              \
    /* P2: read B(hi 32 rows); NO staging */                                   \
    _Pragma("unroll")                                                          \
    for (int n_ = 0; n_ < 2; ++n_) { bfh[n_][0] = RDB(n_,0,1,cur); bfh[n_][1] = RDB(n_,1,1,cur); } \
    __builtin_amdgcn_s_barrier();                                              \
    __builtin_amdgcn_s_setprio(1);                                             \
    MQ(af, bfh, 0, 1)                                                          \
    __builtin_amdgcn_s_setprio(0);                                             \
    __builtin_amdgcn_s_barrier();                                              \
    /* P3: read A(wave half, hi 64 rows); stage BOTH B halves of kt+2          \
       (all B reads of this tile completed before the P2-end barrier) */       \
    _Pragma("unroll")                                                          \
    for (int f_ = 0; f_ < 4; ++f_) { af[f_][0] = RDA(f_,0,1,cur); af[f_][1] = RDA(f_,1,1,cur); } \
    if (st_) { STG_B(0, (kt) + 2) STG_B(1, (kt) + 2) }                         \
    __builtin_amdgcn_s_barrier();                                              \
    __builtin_amdgcn_s_setprio(1);                                             \
    MQ(af, bfl, 1, 0)                                                          \
    __builtin_amdgcn_s_setprio(0);                                             \
    __builtin_amdgcn_s_barrier();                                              \
    /* P4: stage BOTH A halves of kt+2 (all A reads done before P3-end         \
       barrier); counted vmcnt(8) = leave kt+2's 8 loads in flight */          \
    if (st_) { STG_A(0, (kt) + 2) STG_A(1, (kt) + 2)                           \
               asm volatile("s_waitcnt vmcnt(8)" ::: "memory"); }              \
    else     { asm volatile("s_waitcnt vmcnt(0)" ::: "memory"); }              \
    __builtin_amdgcn_s_barrier();                                              \
    __builtin_amdgcn_s_setprio(1);                                             \
    MQ(af, bfh, 1, 1)                                                          \
    __builtin_amdgcn_s_setprio(0);                                             \
    __builtin_amdgcn_s_barrier(); }

  // prologue: K-tiles 0,1 fully staged, full drain once
  STG_A(0, 0) STG_B(0, 0) STG_B(1, 0) STG_A(1, 0)
  STG_A(0, 1) STG_B(0, 1) STG_B(1, 1) STG_A(1, 1)
  asm volatile("s_waitcnt vmcnt(0)" ::: "memory");
  __builtin_amdgcn_s_barrier();

  for (int i2 = 0; i2 < 8; ++i2) {
    KTB(2 * i2, 0)
    KTB(2 * i2 + 1, 1)
  }
  __syncthreads();   // full drain before LDS reuse in epilogue

  // ---- epilogue: C through LDS, two passes ----
  const bool vtile = (n0 >= 2048);
  if (!vtile) {
    const float sc = (n0 < 1024) ? SCL : 1.0f;
    __bf16* Cs = (__bf16*)smem8;        // [128][264]
#pragma unroll
    for (int h = 0; h < 2; ++h) {
      if ((wid >> 2) == h) {
#pragma unroll
        for (int f = 0; f < 8; ++f) {
          const int rl = f * 16 + quad * 4;
#pragma unroll
          for (int nf = 0; nf < 4; ++nf) {
            const int c = wn + nf * 16 + l16;
            const float bv_ = bias[n0 + c];
#pragma unroll
            for (int g = 0; g < 4; ++g)
              Cs[(rl + g) * 264 + c] = (__bf16)((acc[f][nf][g] + bv_) * sc);
          }
        }
      }
      __syncthreads();
#pragma unroll
      for (int p = 0; p < 8; ++p) {
        const int slot = p * 512 + tid;
        const int row = slot >> 5;
        const int c8 = (slot & 31) * 8;
        bf16x8 v = *(const bf16x8*)&Cs[row * 264 + c8];
        *(bf16x8*)&Cb[(size_t)(m0 + h * 128 + row) * 3072 + n0 + c8] = v;
      }
      __syncthreads();
    }
  } else {
    // V tile: transpose to vT[bh][d][s], two 128-col passes
    __bf16* Cs = (__bf16*)smem8;        // [128 d][264 s]
    const int bb = m0 >> 11, ml = m0 & 2047;
#pragma unroll
    for (int chf = 0; chf < 2; ++chf) {
      if (((wid & 3) >> 1) == chf) {
#pragma unroll
        for (int f = 0; f < 8; ++f) {
          const int r = wm + f * 16 + quad * 4;      // local s, 0..255
#pragma unroll
          for (int nf = 0; nf < 4; ++nf) {
            const int cl = (wn + nf * 16 + l16) - chf * 128;  // 0..127
            const float bv_ = bias[n0 + chf * 128 + cl];
            bf16x4 ov = (bf16x4){(__bf16)(acc[f][nf][0] + bv_),
                                 (__bf16)(acc[f][nf][1] + bv_),
                                 (__bf16)(acc[f][nf][2] + bv_),
                                 (__bf16)(acc[f][nf][3] + bv_)};
            *(bf16x4*)&Cs[cl * 264 + r] = ov;
          }
        }
      }
      __syncthreads();
#pragma unroll
      for (int p = 0; p < 8; ++p) {
        const int slot = p * 512 + tid;
        const int dd = slot >> 5;
        const int s8 = (slot & 31) * 8;
        bf16x8 v = *(const bf16x8*)&Cs[dd * 264 + s8];
        const int c2 = n0 - 2048 + chf * 128 + dd;
        const int hh = c2 >> 6, ddd = c2 & 63;
        *(bf16x8*)&vT[((size_t)(bb * 16 + hh) * 64 + ddd) * 2048 + ml + s8] = v;
      }
      __syncthreads();
    }
  }
}

// ---------------- MFMA flash attention, S^T formulation (round-0, 42.0us) ---
__global__ __launch_bounds__(256) void attn_mfma(
    const __bf16* __restrict__ qkv, const __bf16* __restrict__ vT,
    __bf16* __restrict__ zb)
{
  __shared__ __bf16 Qs[64 * 64];      // Q; later per-wave P slices
  __shared__ __bf16 Ks[2][64 * 64];
  __shared__ __bf16 Vs[3][64 * 64];   // [d][k] (from vT)

  const int tid = threadIdx.x;
  const int lane = tid & 63, wave = tid >> 6;
  const int l16 = lane & 15, quad = lane >> 4;
  const int bx = blockIdx.x;
  const int qt = 31 - (bx >> 5);       // heavy q-tiles dispatched first
  const int bh = bx & 31;
  const int h = bh & 15, b = bh >> 4;
  const int q0 = qt * 64;

  const __bf16* qg = qkv + (size_t)b * 2048 * 3072 + h * 64;
  const __bf16* kg = qg + 1024;
  const __bf16* vg = vT + (size_t)bh * 64 * 2048;

#define STAGE_KV(kt_, kbuf, vbuf)                                               \
  { const int kn = (kt_) * 64;                                                  \
    _Pragma("unroll")                                                           \
    for (int i = 0; i < 2; ++i) {                                               \
      int slot = i * 256 + tid;                                                 \
      int row = slot >> 3, ph2 = slot & 7;                                      \
      int cs = ph2 ^ (row & 7);                                                 \
      gload_lds16(kg + (size_t)(kn + row) * 3072 + cs * 8, &Ks[kbuf][slot * 8]);\
      gload_lds16(vg + (size_t)row * 2048 + kn + cs * 8, &Vs[vbuf][slot * 8]);  \
    } }

  // prologue: Q + K/V tile 0
#pragma unroll
  for (int i = 0; i < 2; ++i) {
    int slot = i * 256 + tid;
    int row = slot >> 3, ph2 = slot & 7;
    int cs = ph2 ^ (row & 7);
    gload_lds16(qg + (size_t)(q0 + row) * 3072 + cs * 8, &Qs[slot * 8]);
  }
  STAGE_KV(0, 0, 0)
  __syncthreads();

  const int swz = l16 & 7;
  const int sw0 = ((quad) ^ swz) * 8;
  const int sw1 = ((quad + 4) ^ swz) * 8;
  const int mrow = wave * 16 + l16;

  // Q fragments (loop-invariant), used as the B operand of S^T = K.Q^T
  bf16x8 qf0 = *(const bf16x8*)&Qs[mrow * 64 + sw0];
  bf16x8 qf1 = *(const bf16x8*)&Qs[mrow * 64 + sw1];
  __bf16* P = &Qs[wave * 16 * 64];    // this wave's own 16x64 slice

  // ones B-frag: B[n=0][k]=1 -> col 0 of Ol = row-sum of P (the l vector)
  bf16x8 onesf;
  {
    __bf16 ov = (l16 == 0) ? (__bf16)1.0f : (__bf16)0.0f;
#pragma unroll
    for (int i = 0; i < 8; ++i) onesf[i] = ov;
  }

  const f32x4 zero = {0.f, 0.f, 0.f, 0.f};
  f32x4 O[4], Ol = zero;
#pragma unroll
  for (int j = 0; j < 4; ++j) O[j] = zero;
  f32x4 s_cur[4], s_next[4];   // S^T: lane holds [key=m*16+quad*4+g][q=l16]

#define S_TILE(sdst, kb)                                                        \
  { _Pragma("unroll")                                                           \
    for (int m = 0; m < 4; ++m) sdst[m] = zero;                                 \
    _Pragma("unroll")                                                           \
    for (int m = 0; m < 4; ++m) {                                               \
      bf16x8 kf0 = *(const bf16x8*)&Ks[kb][(m * 16 + l16) * 64 + sw0];          \
      sdst[m] = __builtin_amdgcn_mfma_f32_16x16x32_bf16(kf0, qf0, sdst[m],0,0,0);\
      bf16x8 kf1 = *(const bf16x8*)&Ks[kb][(m * 16 + l16) * 64 + sw1];          \
      sdst[m] = __builtin_amdgcn_mfma_f32_16x16x32_bf16(kf1, qf1, sdst[m],0,0,0);\
    } }

#define EXP_P(s, DIAG)                                                          \
  { _Pragma("unroll")                                                           \
    for (int m = 0; m < 4; ++m) {                                               \
      const int kl = m * 16 + quad * 4;                                         \
      bf16x4 st;                                                                \
      _Pragma("unroll")                                                         \
      for (int g = 0; g < 4; ++g) {                                             \
        float p = __builtin_exp2f(s[m][g]);                                     \
        if (DIAG && (kl + g) > (wave * 16 + l16)) p = 0.f;                      \
        st[g] = (__bf16)p;                                                      \
      }                                                                         \
      *(bf16x4*)&P[l16 * 64 + (((2 * m + (quad >> 1)) ^ swz) * 8) + (quad & 1) * 4] = st; \
    } }

#define PV_TILE(vb)                                                             \
  { bf16x8 pf0 = *(const bf16x8*)&P[l16 * 64 + sw0];                            \
    bf16x8 pf1 = *(const bf16x8*)&P[l16 * 64 + sw1];                            \
    _Pragma("unroll")                                                           \
    for (int j = 0; j < 4; ++j) {                                               \
      bf16x8 vf0 = *(const bf16x8*)&Vs[vb][(j * 16 + l16) * 64 + sw0];          \
      O[j] = __builtin_amdgcn_mfma_f32_16x16x32_bf16(pf0, vf0, O[j], 0, 0, 0);  \
      bf16x8 vf1 = *(const bf16x8*)&Vs[vb][(j * 16 + l16) * 64 + sw1];          \
      O[j] = __builtin_amdgcn_mfma_f32_16x16x32_bf16(pf1, vf1, O[j], 0, 0, 0);  \
    }                                                                           \
    Ol = __builtin_amdgcn_mfma_f32_16x16x32_bf16(pf0, onesf, Ol, 0, 0, 0);      \
    Ol = __builtin_amdgcn_mfma_f32_16x16x32_bf16(pf1, onesf, Ol, 0, 0, 0); }

  // pipeline prologue: stage tile 1, compute S^T(0)
  if (qt > 0) STAGE_KV(1, 1, 1)
  S_TILE(s_cur, 0)
  if (qt > 0) __syncthreads();   // drains stage(1)

  for (int t = 0; t < qt; ++t) {
    EXP_P(s_cur, false)                    // VALU of tile t ...
    S_TILE(s_next, (t + 1) & 1)            // ... overlaps MFMA of tile t+1
    PV_TILE(t % 3)
    if (t + 2 <= qt) STAGE_KV(t + 2, t & 1, (t + 2) % 3)
    __syncthreads();
#pragma unroll
    for (int m = 0; m < 4; ++m) s_cur[m] = s_next[m];
  }
  // diagonal (masked) tile
  EXP_P(s_cur, true)
  PV_TILE(qt % 3)

  // epilogue: l lives in col 0 of Ol (lanes l16==0); broadcast within quad
  const int rq = q0 + wave * 16 + quad * 4;
#pragma unroll
  for (int g = 0; g < 4; ++g) {
    const float lv = __shfl(Ol[g], quad * 16);
    const float inv = 1.0f / lv;
    const size_t rb = (size_t)(b * 2048 + rq + g) * 1024 + h * 64 + l16;
#pragma unroll
    for (int j = 0; j < 4; ++j)
      zb[rb + j * 16] = (__bf16)(O[j][g] * inv);
  }
}

// ---------------- launch ----------------
extern "C" void kernel_launch(void* const* d_in, const int* in_sizes, int n_in,
                              void* d_out, int out_size, void* d_ws, size_t ws_size,
                              hipStream_t stream) {
  (void)in_sizes; (void)n_in; (void)out_size; (void)ws_size;
  const float* x  = (const float*)d_in[0];
  const float* Wq = (const float*)d_in[1];
  const float* bq = (const float*)d_in[2];
  const float* Wk = (const float*)d_in[3];
  const float* bk = (const float*)d_in[4];
  const float* Wv = (const float*)d_in[5];
  const float* bv = (const float*)d_in[6];
  const float* Wo = (const float*)d_in[7];
  const float* bo = (const float*)d_in[8];

  char* ws = (char*)d_ws;
  __bf16* xb   = (__bf16*)(ws);                        // 8 MB
  __bf16* wqkv = (__bf16*)(ws + (8ull  << 20));        // 6 MB
  __bf16* wob  = (__bf16*)(ws + (14ull << 20));        // 2 MB
  float*  bqkv = (float*) (ws + (16ull << 20));        // 12 KB
  __bf16* qkv  = (__bf16*)(ws + (17ull << 20));        // 24 MB
  __bf16* vT   = (__bf16*)(ws + (41ull << 20));        // 8 MB  [bh][64][2048]
  __bf16* zb   = (__bf16*)(ws + (49ull << 20));        // 8 MB  (total 57 MB)

  cvt_kernel<<<4097, 256, 0, stream>>>(x, Wq, Wk, Wv, Wo, bq, bk, bv,
                                       xb, wqkv, wob, bqkv);
  gemm8_qkv<<<192, 512, 0, stream>>>(xb, wqkv, bqkv, qkv, vT);
  attn_mfma<<<1024, 256, 0, stream>>>(qkv, vT, zb);
  gemm_k<128, 64, 0><<<dim3(16, 32), 256, 0, stream>>>(
      zb, wob, bo, (float*)d_out, nullptr, nullptr, Mx, 1024, 1024, 1024);
}